// Round 6
// baseline (430.527 us; speedup 1.0000x reference)
//
#include <hip/hip_runtime.h>
#include <math.h>

// DeepSeek-V3 MoE gate on gfx950.
// Round 10: REGISTER-BUDGET redesign. r9's decisive counter: VGPR_Count=128
// for a pipeline needing ~280 live (acc 128 + B-dbuf 64 + X + frags). The
// compiler fit it by SINKING the B/X prefetches to just-before-use ->
// distance-0 -> exposed L2/HBM latency every tile (~6900 cyc/tile vs ~800
// modeled). This explains why r4/r5/r8/r9's different source pipelines all
// benched the same: they all compiled to the same reg-starved schedule.
// Fix:
//  - 512 thr / 8 waves as 1m x 8n: wave tile 64m x 32n -> acc 64 VGPR (was
//    128), B-dbuf 32 (was 64), X 8. Peak live ~170 < 256.
//  - amdgpu_waves_per_eu(2,2): regalloc budget pinned to 256 VGPR; scheduler
//    must NOT chase 4 waves/EU by squeezing to 128.
//  - bonus: waves own disjoint 32-expert slices -> B-L2 per CU per tile
//    halves to 32KB; X per block halves to 8KB.
// Sync structure unchanged from r9 (LGKM_BARRIER, B dist-1, X dist-2).
// Numerics unchanged: fp16 hi + 2^11-scaled lo split, 3 MFMAs per logical.

#define N_EXPERTS 256
#define TOPK_GROUP 4
#define TOP_K 8

#define KDIM 7168
#define BM 64
#define BK 32
#define NCHUNK 4
#define KC (KDIM / NCHUNK)        // 1792
#define KTILES (KC / BK)          // 56 k-tiles per chunk (even, for unroll-2)
// Wb blob: [tile][wq 0..3][plane 0..1][j 0..3][l4 0..3][l16 0..15][jj 0..7] f16
// -> per (tile,wq,plane,j): 1KB read by 64 lanes as contiguous dwordx4 (l*8 shorts)
#define TILE_SHORTS 16384
#define LO_SCALE 2048.0f
#define LO_INV (1.0f / 2048.0f)

typedef _Float16 f16x8 __attribute__((ext_vector_type(8)));  // 8 f16 (4 VGPRs)
typedef _Float16 f16x4 __attribute__((ext_vector_type(4)));  // 4 f16 (2 VGPRs)
typedef float f32x4 __attribute__((ext_vector_type(4)));

// W [256][7168] fp32 -> swizzled hi/lo f16 blob (see layout above)
__global__ __launch_bounds__(256)
void convert_w(const float* __restrict__ W, unsigned short* __restrict__ Wb) {
    int g = blockIdx.x * 256 + threadIdx.x;  // n * (KDIM/8) + k8
    int n = g / (KDIM / 8);
    int k8 = g % (KDIM / 8);
    const float* src = W + (long)n * KDIM + k8 * 8;
    float4 v0 = *(const float4*)src;
    float4 v1 = *(const float4*)(src + 4);
    float x[8] = {v0.x, v0.y, v0.z, v0.w, v1.x, v1.y, v1.z, v1.w};
    f16x8 hv, lv;
#pragma unroll
    for (int j = 0; j < 8; ++j) {
        _Float16 h = (_Float16)x[j];
        hv[j] = h;
        lv[j] = (_Float16)((x[j] - (float)h) * LO_SCALE);  // exact split, *2^11 exact
    }
    int tk = k8 >> 2, l4 = k8 & 3;
    int w = n >> 6, j = (n >> 4) & 3, l16 = n & 15;
    unsigned short* d = Wb + (long)tk * TILE_SHORTS + w * 4096 + j * 512 + l4 * 128 + l16 * 8;
    *(f16x8*)d = hv;            // plane 0 (hi)
    *(f16x8*)(d + 2048) = lv;   // plane 1 (lo), +pl stride 4*4*128
}

// lgkm-only publish barrier: NO memory clobber (a clobber makes the waitcnt
// pass insert vmcnt(0) before the asm = full prefetch drain). sched_barrier
// pins ds ops on their side of the fence.
#define LGKM_BARRIER()                                    \
    do {                                                  \
        __builtin_amdgcn_sched_barrier(0);                \
        asm volatile("s_waitcnt lgkmcnt(0)");             \
        __builtin_amdgcn_sched_barrier(0);                \
        __builtin_amdgcn_s_barrier();                     \
        __builtin_amdgcn_sched_barrier(0);                \
    } while (0)

// One tile body. CUR_/NXT_: As parity. BCUR_/BNXT_: named B reg sets
// (4 x f16x8: [pl0 j0, pl0 j1, pl1 j0, pl1 j1]). XV_: X prefetch float4
// whose parity matches tile T_+1 (stage consumes it, then reloads T_+3).
#define GEMM_BODY(T_, CUR_, NXT_, BCUR_, BNXT_, XV_)                                 \
    {                                                                                \
        const int t_ = (T_);                                                         \
        /* A fragments for tile t_ (8 x ds_read_b128, conflict-uniform) */           \
        f16x8 ah[4], al[4];                                                          \
        _Pragma("unroll")                                                            \
        for (int i = 0; i < 4; ++i) {                                                \
            const char* pa_ =                                                        \
                (const char*)&As[CUR_][0][0] + (i * 16 + l16) * 80 + l4 * 16;        \
            ah[i] = *(const f16x8*)pa_;                                              \
            al[i] = *(const f16x8*)(pa_ + 5120);                                     \
        }                                                                            \
        if (t_ + 1 < KTILES) {                                                       \
            /* stage A(t_+1): XV_ loaded ~2 bodies ago -> vmcnt wait ~0 */           \
            f16x4 hv, lv;                                                            \
            float xv[4] = {XV_.x, XV_.y, XV_.z, XV_.w};                              \
            _Pragma("unroll")                                                        \
            for (int q = 0; q < 4; ++q) {                                            \
                _Float16 h = (_Float16)xv[q];                                        \
                hv[q] = h;                                                           \
                lv[q] = (_Float16)((xv[q] - (float)h) * LO_SCALE);                   \
            }                                                                        \
            *(f16x4*)&As[NXT_][0][sm * 40 + skq * 4] = hv;                           \
            *(f16x4*)&As[NXT_][1][sm * 40 + skq * 4] = lv;                           \
            /* reload this X set with tile t_+3 (~2 bodies in flight) */             \
            const int kn_ = (t_ + 3 < KTILES) ? t_ + 3 : KTILES - 1;                 \
            XV_ = *(const float4*)(Xp + kn_ * BK);                                   \
            /* B(t_+1) -> other reg set (L2-resident, 1 body in flight) */           \
            const unsigned short* bp_ = Bp + (long)(t_ + 1) * TILE_SHORTS;           \
            _Pragma("unroll")                                                        \
            for (int pl = 0; pl < 2; ++pl)                                           \
                _Pragma("unroll")                                                    \
                for (int j = 0; j < 2; ++j)                                          \
                    BNXT_[pl * 2 + j] = *(const f16x8*)(bp_ + pl * 2048 + j * 512);  \
        }                                                                            \
        _Pragma("unroll")                                                            \
        for (int i = 0; i < 4; ++i)                                                  \
            _Pragma("unroll")                                                        \
            for (int j = 0; j < 2; ++j) {                                            \
                acc1[i][j] = __builtin_amdgcn_mfma_f32_16x16x32_f16(                 \
                    ah[i], BCUR_[2 + j], acc1[i][j], 0, 0, 0);                       \
                acc1[i][j] = __builtin_amdgcn_mfma_f32_16x16x32_f16(                 \
                    al[i], BCUR_[j], acc1[i][j], 0, 0, 0);                           \
                acc0[i][j] = __builtin_amdgcn_mfma_f32_16x16x32_f16(                 \
                    ah[i], BCUR_[j], acc0[i][j], 0, 0, 0);                           \
            }                                                                        \
        if (t_ + 1 < KTILES) {                                                       \
            /* publish As[NXT_]: lgkm drain only, global prefetches keep flying */   \
            LGKM_BARRIER();                                                          \
        }                                                                            \
    }

__global__ __launch_bounds__(512)
__attribute__((amdgpu_waves_per_eu(2, 2)))
void gemm_mfma(const float* __restrict__ X, const unsigned short* __restrict__ Wb,
               float* __restrict__ part, int T) {
    // A double-buffered: [buf][plane][m 0..63][40 f16] (pad 32->40), 20 KB total
    __shared__ __align__(16) unsigned short As[2][2][64 * 40];

    const int tid = threadIdx.x;
    // XCD swizzle: chunk kc owns XCDs {2kc,2kc+1} -> its 1.8MB Wb slice L2-resident
    const int lin = blockIdx.x;
    const int xcd = lin & 7;
    const int kc = xcd >> 1;
    const int mb = ((lin >> 3) << 1) | (xcd & 1);
    const int m0 = mb * BM;

    const int w = tid >> 6;          // wave 0..7 -> expert slice w*32
    const int l = tid & 63;
    const int l16 = l & 15, l4 = l >> 4;

    // A staging: thread (m = tid>>3, kq = tid&7) loads 4 consecutive k floats
    const int sm = tid >> 3, skq = tid & 7;
    const float* Xp = X + (long)(m0 + sm) * KDIM + kc * KC + skq * 4;

    // B: per-lane base for this wave's 32-expert slice.
    // blob: [tile][wq]*4096 + [pl]*2048 + [j]*512 + l*8; wq = w>>1, j-base = (w&1)*2
    const unsigned short* Bp = Wb + (long)(kc * KTILES) * TILE_SHORTS +
                               (w >> 1) * 4096 + (w & 1) * 1024 + l * 8;

    f32x4 acc0[4][2], acc1[4][2];
#pragma unroll
    for (int i = 0; i < 4; ++i)
#pragma unroll
        for (int j = 0; j < 2; ++j) {
            acc0[i][j] = (f32x4){0.f, 0.f, 0.f, 0.f};
            acc1[i][j] = (f32x4){0.f, 0.f, 0.f, 0.f};
        }

    // ---- prologue ----
    {
        // tile 0 -> As[0]
        float4 a0 = *(const float4*)Xp;
        f16x4 hv, lv;
        float xv[4] = {a0.x, a0.y, a0.z, a0.w};
#pragma unroll
        for (int q = 0; q < 4; ++q) {
            _Float16 h = (_Float16)xv[q];
            hv[q] = h;
            lv[q] = (_Float16)((xv[q] - (float)h) * LO_SCALE);
        }
        *(f16x4*)&As[0][0][sm * 40 + skq * 4] = hv;
        *(f16x4*)&As[0][1][sm * 40 + skq * 4] = lv;
    }
    // X prefetch sets: xO holds odd tiles (starts at 1), xE even (starts at 2)
    float4 xO = *(const float4*)(Xp + 1 * BK);
    float4 xE = *(const float4*)(Xp + 2 * BK);
    // B double-buffer reg sets; bb0 <- B(0)
    f16x8 bb0[4], bb1[4];
#pragma unroll
    for (int pl = 0; pl < 2; ++pl)
#pragma unroll
        for (int j = 0; j < 2; ++j)
            bb0[pl * 2 + j] = *(const f16x8*)(Bp + pl * 2048 + j * 512);

    LGKM_BARRIER();

#pragma unroll 1
    for (int kt = 0; kt < KTILES; kt += 2) {
        GEMM_BODY(kt,     0, 1, bb0, bb1, xO)   // even tile: consumes X(kt+1) [odd set]
        GEMM_BODY(kt + 1, 1, 0, bb1, bb0, xE)   // odd tile:  consumes X(kt+2) [even set]
    }

    // epilogue: part[kc][m0+m][n]  (C/D layout: col=lane&15, row=(lane>>4)*4+reg)
    float* P = part + ((long)kc * T + m0) * N_EXPERTS;
#pragma unroll
    for (int i = 0; i < 4; ++i) {
        int m = i * 16 + l4 * 4;
#pragma unroll
        for (int j = 0; j < 2; ++j) {
            int n = w * 32 + j * 16 + l16;
#pragma unroll
            for (int r = 0; r < 4; ++r)
                P[(long)(m + r) * N_EXPERTS + n] =
                    acc0[i][j][r] + acc1[i][j][r] * LO_INV;
        }
    }
}

// One wave (64 lanes) per token; lane l owns experts 4l..4l+3 (group = l>>3).
__global__ __launch_bounds__(256)
void routing_kernel(const float* __restrict__ part, const float* __restrict__ bias,
                    float* __restrict__ out, int T) {
    const int lane = threadIdx.x & 63;
    const int wv = threadIdx.x >> 6;
    const int t = blockIdx.x * 4 + wv;
    if (t >= T) return;
    const long TN = (long)T * N_EXPERTS;

    const float* p = part + (long)t * N_EXPERTS + lane * 4;
    float lg[4] = {0.f, 0.f, 0.f, 0.f};
#pragma unroll
    for (int c = 0; c < NCHUNK; ++c) {
        float4 v = *(const float4*)(p + c * TN);
        lg[0] += v.x; lg[1] += v.y; lg[2] += v.z; lg[3] += v.w;
    }
    float4 bv = *(const float4*)(bias + lane * 4);
    const float bb[4] = {bv.x, bv.y, bv.z, bv.w};

    float s[4], sc[4];
#pragma unroll
    for (int j = 0; j < 4; ++j) {
        s[j] = 1.f / (1.f + expf(-lg[j]));
        sc[j] = s[j] + bb[j];
    }

    // group score = sum of top-2 biased scores within the 32-expert group
    float m1 = fmaxf(sc[0], sc[1]), m2 = fminf(sc[0], sc[1]);
    if (sc[2] > m1) { m2 = m1; m1 = sc[2]; } else m2 = fmaxf(m2, sc[2]);
    if (sc[3] > m1) { m2 = m1; m1 = sc[3]; } else m2 = fmaxf(m2, sc[3]);
#pragma unroll
    for (int o = 1; o <= 4; o <<= 1) {
        float o1 = __shfl_xor(m1, o);
        float o2 = __shfl_xor(m2, o);
        float n1 = fmaxf(m1, o1);
        float n2 = fmaxf(fminf(m1, o1), fmaxf(m2, o2));
        m1 = n1; m2 = n2;
    }
    float gsum = m1 + m2;

    float gs[8];
#pragma unroll
    for (int g = 0; g < 8; ++g) gs[g] = __shfl(gsum, g * 8);

    int selmask = 0;
#pragma unroll
    for (int g = 0; g < 8; ++g) {
        int rank = 0;
#pragma unroll
        for (int h = 0; h < 8; ++h)
            rank += (gs[h] > gs[g]) || (gs[h] == gs[g] && h < g);
        if (rank < TOPK_GROUP) selmask |= 1 << g;
    }

    const int mygrp = lane >> 3;
    float val[4];
#pragma unroll
    for (int j = 0; j < 4; ++j)
        val[j] = ((selmask >> mygrp) & 1) ? sc[j] : -INFINITY;

    float wsel[TOP_K];
    int isel[TOP_K];
    float denom = 1e-20f;
#pragma unroll
    for (int it = 0; it < TOP_K; ++it) {
        float bvv = val[0];
        int bi = lane * 4;
#pragma unroll
        for (int j = 1; j < 4; ++j)
            if (val[j] > bvv) { bvv = val[j]; bi = lane * 4 + j; }
#pragma unroll
        for (int o = 1; o < 64; o <<= 1) {
            float ov = __shfl_xor(bvv, o);
            int oi = __shfl_xor(bi, o);
            if (ov > bvv || (ov == bvv && oi < bi)) { bvv = ov; bi = oi; }
        }
        isel[it] = bi;
        int q = bi & 3, ol = bi >> 2;
        float sv = (q == 0) ? s[0] : (q == 1) ? s[1] : (q == 2) ? s[2] : s[3];
        float w = __shfl(sv, ol);
        wsel[it] = w;
        denom += w;
        if (lane == ol) {
            if (q == 0) val[0] = -INFINITY;
            else if (q == 1) val[1] = -INFINITY;
            else if (q == 2) val[2] = -INFINITY;
            else val[3] = -INFINITY;
        }
    }

    if (lane == 0) {
        float scale = 2.5f / denom;
        long base = (long)t * TOP_K;
        long wbase = (long)T * TOP_K + base;
#pragma unroll
        for (int it = 0; it < TOP_K; ++it) {
            out[base + it] = (float)isel[it];
            out[wbase + it] = wsel[it] * scale;
        }
    }
}

extern "C" void kernel_launch(void* const* d_in, const int* in_sizes, int n_in,
                              void* d_out, int out_size, void* d_ws, size_t ws_size,
                              hipStream_t stream) {
    const float* X = (const float*)d_in[0];     // [T, 7168] fp32
    const float* W = (const float*)d_in[1];     // [256, 7168] fp32
    const float* bias = (const float*)d_in[2];  // [256] fp32
    float* out = (float*)d_out;

    const int K = in_sizes[1] / N_EXPERTS;  // 7168
    const int T = in_sizes[0] / K;          // 8192

    float* part = (float*)d_ws;                                    // 32 MB
    unsigned short* Wb = (unsigned short*)((char*)d_ws + (size_t)NCHUNK * T * N_EXPERTS * 4);  // 7.34 MB

    convert_w<<<(N_EXPERTS * (KDIM / 8)) / 256, 256, 0, stream>>>(W, Wb);
    gemm_mfma<<<(T / BM) * NCHUNK, 512, 0, stream>>>(X, Wb, part, T);
    routing_kernel<<<T / 4, 256, 0, stream>>>(part, bias, out, T);
}

// Round 7
// 394.846 us; speedup vs baseline: 1.0904x; 1.0904x over previous
//
#include <hip/hip_runtime.h>
#include <math.h>

// DeepSeek-V3 MoE gate on gfx950.
// Round 11: OCCUPANCY + L2-POLLUTION fix. r10's counters decoded:
//  - VGPR_Count=88 is ARCH vgprs only; acc lives in 64 AGPRs (unified file)
//    -> 152 total regs/wave -> only 2 waves/SIMD fit (pool 512/SIMD, m69
//    thresholds 64/128/256) -> ONE barrier-locked block/CU, zero TLP.
//    Occupancy 22% measured == exactly this. All stalls are exposed.
//  - B "L2-resident" assumption is false: X streams 235MB through the same
//    L2s (29MB/XCD/pass vs 4MB) and evicts the 1.8MB B slice -> B loads see
//    L3 latency (~600-900cyc), exposed every tile in the lockstep block.
// Fixes:
//  - __launch_bounds__(512,4): total reg budget 128/wave -> 2 independent
//    blocks/CU (4 waves/SIMD). Body restructured for a low-reg schedule:
//    staging+prefetch first, then frag-pair ds_read -> MFMA x2, so minimal
//    live set ~120 fits the budget (acc 64 AGPR + ~56 arch VGPR).
//  - Nontemporal X loads + part stores (zero-reuse streams) -> B stays
//    L2-resident -> distance-1 B prefetch is covered again.
// Numerics unchanged: fp16 hi + 2^11-scaled lo split, 3 MFMAs per logical.

#define N_EXPERTS 256
#define TOPK_GROUP 4
#define TOP_K 8

#define KDIM 7168
#define BM 64
#define BK 32
#define NCHUNK 4
#define KC (KDIM / NCHUNK)        // 1792
#define KTILES (KC / BK)          // 56 k-tiles per chunk (even, for unroll-2)
// Wb blob: [tile][wq 0..3][plane 0..1][j 0..3][l4 0..3][l16 0..15][jj 0..7] f16
// -> per (tile,wq,plane,j): 1KB read by 64 lanes as contiguous dwordx4 (l*8 shorts)
#define TILE_SHORTS 16384
#define LO_SCALE 2048.0f
#define LO_INV (1.0f / 2048.0f)

typedef _Float16 f16x8 __attribute__((ext_vector_type(8)));  // 8 f16 (4 VGPRs)
typedef _Float16 f16x4 __attribute__((ext_vector_type(4)));  // 4 f16 (2 VGPRs)
typedef float f32x4 __attribute__((ext_vector_type(4)));

// W [256][7168] fp32 -> swizzled hi/lo f16 blob (see layout above)
__global__ __launch_bounds__(256)
void convert_w(const float* __restrict__ W, unsigned short* __restrict__ Wb) {
    int g = blockIdx.x * 256 + threadIdx.x;  // n * (KDIM/8) + k8
    int n = g / (KDIM / 8);
    int k8 = g % (KDIM / 8);
    const float* src = W + (long)n * KDIM + k8 * 8;
    float4 v0 = *(const float4*)src;
    float4 v1 = *(const float4*)(src + 4);
    float x[8] = {v0.x, v0.y, v0.z, v0.w, v1.x, v1.y, v1.z, v1.w};
    f16x8 hv, lv;
#pragma unroll
    for (int j = 0; j < 8; ++j) {
        _Float16 h = (_Float16)x[j];
        hv[j] = h;
        lv[j] = (_Float16)((x[j] - (float)h) * LO_SCALE);  // exact split, *2^11 exact
    }
    int tk = k8 >> 2, l4 = k8 & 3;
    int w = n >> 6, j = (n >> 4) & 3, l16 = n & 15;
    unsigned short* d = Wb + (long)tk * TILE_SHORTS + w * 4096 + j * 512 + l4 * 128 + l16 * 8;
    *(f16x8*)d = hv;            // plane 0 (hi)
    *(f16x8*)(d + 2048) = lv;   // plane 1 (lo), +pl stride 4*4*128
}

// lgkm-only publish barrier: NO memory clobber (a clobber makes the waitcnt
// pass insert vmcnt(0) before the asm = full prefetch drain). sched_barrier
// pins ds ops on their side of the fence.
#define LGKM_BARRIER()                                    \
    do {                                                  \
        __builtin_amdgcn_sched_barrier(0);                \
        asm volatile("s_waitcnt lgkmcnt(0)");             \
        __builtin_amdgcn_sched_barrier(0);                \
        __builtin_amdgcn_s_barrier();                     \
        __builtin_amdgcn_sched_barrier(0);                \
    } while (0)

// One tile body. CUR_/NXT_: As parity. BCUR_/BNXT_: named B reg sets
// (4 x f16x8: [pl0 j0, pl0 j1, pl1 j0, pl1 j1]). XV_: X prefetch f32x4
// whose parity matches tile T_+1 (stage consumes it, then reloads T_+3,
// nontemporal: X is a zero-reuse stream, keep it out of L2).
// Order: staging+prefetch FIRST, then frag-pair ds_read -> 12 MFMAs, twice.
// This gives the register allocator a schedule with only ~1-2 frag pairs
// live at once (fits the 128-reg/wave budget of launch_bounds(512,4)).
#define GEMM_BODY(T_, CUR_, NXT_, BCUR_, BNXT_, XV_)                                 \
    {                                                                                \
        const int t_ = (T_);                                                         \
        if (t_ + 1 < KTILES) {                                                       \
            /* stage A(t_+1): XV_ loaded ~2 bodies ago -> vmcnt wait ~0 */           \
            f16x4 hv, lv;                                                            \
            float xv[4] = {XV_[0], XV_[1], XV_[2], XV_[3]};                          \
            _Pragma("unroll")                                                        \
            for (int q = 0; q < 4; ++q) {                                            \
                _Float16 h = (_Float16)xv[q];                                        \
                hv[q] = h;                                                           \
                lv[q] = (_Float16)((xv[q] - (float)h) * LO_SCALE);                   \
            }                                                                        \
            *(f16x4*)&As[NXT_][0][sm * 40 + skq * 4] = hv;                           \
            *(f16x4*)&As[NXT_][1][sm * 40 + skq * 4] = lv;                           \
            /* reload this X set with tile t_+3 (~2 bodies in flight), NT */         \
            const int kn_ = (t_ + 3 < KTILES) ? t_ + 3 : KTILES - 1;                 \
            XV_ = __builtin_nontemporal_load((const f32x4*)(Xp + kn_ * BK));         \
            /* B(t_+1) -> other reg set (L2-resident, 1 body in flight) */           \
            const unsigned short* bp_ = Bp + (long)(t_ + 1) * TILE_SHORTS;           \
            _Pragma("unroll")                                                        \
            for (int pl = 0; pl < 2; ++pl)                                           \
                _Pragma("unroll")                                                    \
                for (int j = 0; j < 2; ++j)                                          \
                    BNXT_[pl * 2 + j] = *(const f16x8*)(bp_ + pl * 2048 + j * 512);  \
        }                                                                            \
        _Pragma("unroll")                                                            \
        for (int ii = 0; ii < 4; ii += 2) {                                          \
            /* two frag pairs live at a time (16 VGPR), 24 MFMAs */                  \
            f16x8 ah0, al0, ah1, al1;                                                \
            {                                                                        \
                const char* pa_ =                                                    \
                    (const char*)&As[CUR_][0][0] + (ii * 16 + l16) * 80 + l4 * 16;   \
                ah0 = *(const f16x8*)pa_;                                            \
                al0 = *(const f16x8*)(pa_ + 5120);                                   \
                ah1 = *(const f16x8*)(pa_ + 16 * 80);                                \
                al1 = *(const f16x8*)(pa_ + 16 * 80 + 5120);                         \
            }                                                                        \
            _Pragma("unroll")                                                        \
            for (int j = 0; j < 2; ++j) {                                            \
                acc1[ii][j] = __builtin_amdgcn_mfma_f32_16x16x32_f16(                \
                    ah0, BCUR_[2 + j], acc1[ii][j], 0, 0, 0);                        \
                acc1[ii][j] = __builtin_amdgcn_mfma_f32_16x16x32_f16(                \
                    al0, BCUR_[j], acc1[ii][j], 0, 0, 0);                            \
                acc0[ii][j] = __builtin_amdgcn_mfma_f32_16x16x32_f16(                \
                    ah0, BCUR_[j], acc0[ii][j], 0, 0, 0);                            \
                acc1[ii + 1][j] = __builtin_amdgcn_mfma_f32_16x16x32_f16(            \
                    ah1, BCUR_[2 + j], acc1[ii + 1][j], 0, 0, 0);                    \
                acc1[ii + 1][j] = __builtin_amdgcn_mfma_f32_16x16x32_f16(            \
                    al1, BCUR_[j], acc1[ii + 1][j], 0, 0, 0);                        \
                acc0[ii + 1][j] = __builtin_amdgcn_mfma_f32_16x16x32_f16(            \
                    ah1, BCUR_[j], acc0[ii + 1][j], 0, 0, 0);                        \
            }                                                                        \
        }                                                                            \
        if (t_ + 1 < KTILES) {                                                       \
            /* publish As[NXT_]: lgkm drain only, global prefetches keep flying */   \
            LGKM_BARRIER();                                                          \
        }                                                                            \
    }

__global__ __launch_bounds__(512, 4)
void gemm_mfma(const float* __restrict__ X, const unsigned short* __restrict__ Wb,
               float* __restrict__ part, int T) {
    // A double-buffered: [buf][plane][m 0..63][40 f16] (pad 32->40), 20 KB total
    __shared__ __align__(16) unsigned short As[2][2][64 * 40];

    const int tid = threadIdx.x;
    // XCD swizzle: chunk kc owns XCDs {2kc,2kc+1} -> its 1.8MB Wb slice L2-resident
    const int lin = blockIdx.x;
    const int xcd = lin & 7;
    const int kc = xcd >> 1;
    const int mb = ((lin >> 3) << 1) | (xcd & 1);
    const int m0 = mb * BM;

    const int w = tid >> 6;          // wave 0..7 -> expert slice w*32
    const int l = tid & 63;
    const int l16 = l & 15, l4 = l >> 4;

    // A staging: thread (m = tid>>3, kq = tid&7) loads 4 consecutive k floats
    const int sm = tid >> 3, skq = tid & 7;
    const float* Xp = X + (long)(m0 + sm) * KDIM + kc * KC + skq * 4;

    // B: per-lane base for this wave's 32-expert slice.
    // blob: [tile][wq]*4096 + [pl]*2048 + [j]*512 + l*8; wq = w>>1, j-base = (w&1)*2
    const unsigned short* Bp = Wb + (long)(kc * KTILES) * TILE_SHORTS +
                               (w >> 1) * 4096 + (w & 1) * 1024 + l * 8;

    f32x4 acc0[4][2], acc1[4][2];
#pragma unroll
    for (int i = 0; i < 4; ++i)
#pragma unroll
        for (int j = 0; j < 2; ++j) {
            acc0[i][j] = (f32x4){0.f, 0.f, 0.f, 0.f};
            acc1[i][j] = (f32x4){0.f, 0.f, 0.f, 0.f};
        }

    // ---- prologue ----
    {
        // tile 0 -> As[0]
        f32x4 a0 = __builtin_nontemporal_load((const f32x4*)Xp);
        f16x4 hv, lv;
        float xv[4] = {a0[0], a0[1], a0[2], a0[3]};
#pragma unroll
        for (int q = 0; q < 4; ++q) {
            _Float16 h = (_Float16)xv[q];
            hv[q] = h;
            lv[q] = (_Float16)((xv[q] - (float)h) * LO_SCALE);
        }
        *(f16x4*)&As[0][0][sm * 40 + skq * 4] = hv;
        *(f16x4*)&As[0][1][sm * 40 + skq * 4] = lv;
    }
    // X prefetch sets: xO holds odd tiles (starts at 1), xE even (starts at 2)
    f32x4 xO = __builtin_nontemporal_load((const f32x4*)(Xp + 1 * BK));
    f32x4 xE = __builtin_nontemporal_load((const f32x4*)(Xp + 2 * BK));
    // B double-buffer reg sets; bb0 <- B(0)
    f16x8 bb0[4], bb1[4];
#pragma unroll
    for (int pl = 0; pl < 2; ++pl)
#pragma unroll
        for (int j = 0; j < 2; ++j)
            bb0[pl * 2 + j] = *(const f16x8*)(Bp + pl * 2048 + j * 512);

    LGKM_BARRIER();

#pragma unroll 1
    for (int kt = 0; kt < KTILES; kt += 2) {
        GEMM_BODY(kt,     0, 1, bb0, bb1, xO)   // even tile: consumes X(kt+1) [odd set]
        GEMM_BODY(kt + 1, 1, 0, bb1, bb0, xE)   // odd tile:  consumes X(kt+2) [even set]
    }

    // epilogue: part[kc][m0+m][n]  (C/D layout: col=lane&15, row=(lane>>4)*4+reg)
    // nontemporal: part is consumed much later by routing_kernel; don't pollute L2.
    float* P = part + ((long)kc * T + m0) * N_EXPERTS;
#pragma unroll
    for (int i = 0; i < 4; ++i) {
        int m = i * 16 + l4 * 4;
#pragma unroll
        for (int j = 0; j < 2; ++j) {
            int n = w * 32 + j * 16 + l16;
#pragma unroll
            for (int r = 0; r < 4; ++r)
                __builtin_nontemporal_store(
                    acc0[i][j][r] + acc1[i][j][r] * LO_INV,
                    &P[(long)(m + r) * N_EXPERTS + n]);
        }
    }
}

// One wave (64 lanes) per token; lane l owns experts 4l..4l+3 (group = l>>3).
__global__ __launch_bounds__(256)
void routing_kernel(const float* __restrict__ part, const float* __restrict__ bias,
                    float* __restrict__ out, int T) {
    const int lane = threadIdx.x & 63;
    const int wv = threadIdx.x >> 6;
    const int t = blockIdx.x * 4 + wv;
    if (t >= T) return;
    const long TN = (long)T * N_EXPERTS;

    const float* p = part + (long)t * N_EXPERTS + lane * 4;
    float lg[4] = {0.f, 0.f, 0.f, 0.f};
#pragma unroll
    for (int c = 0; c < NCHUNK; ++c) {
        float4 v = *(const float4*)(p + c * TN);
        lg[0] += v.x; lg[1] += v.y; lg[2] += v.z; lg[3] += v.w;
    }
    float4 bv = *(const float4*)(bias + lane * 4);
    const float bb[4] = {bv.x, bv.y, bv.z, bv.w};

    float s[4], sc[4];
#pragma unroll
    for (int j = 0; j < 4; ++j) {
        s[j] = 1.f / (1.f + expf(-lg[j]));
        sc[j] = s[j] + bb[j];
    }

    // group score = sum of top-2 biased scores within the 32-expert group
    float m1 = fmaxf(sc[0], sc[1]), m2 = fminf(sc[0], sc[1]);
    if (sc[2] > m1) { m2 = m1; m1 = sc[2]; } else m2 = fmaxf(m2, sc[2]);
    if (sc[3] > m1) { m2 = m1; m1 = sc[3]; } else m2 = fmaxf(m2, sc[3]);
#pragma unroll
    for (int o = 1; o <= 4; o <<= 1) {
        float o1 = __shfl_xor(m1, o);
        float o2 = __shfl_xor(m2, o);
        float n1 = fmaxf(m1, o1);
        float n2 = fmaxf(fminf(m1, o1), fmaxf(m2, o2));
        m1 = n1; m2 = n2;
    }
    float gsum = m1 + m2;

    float gs[8];
#pragma unroll
    for (int g = 0; g < 8; ++g) gs[g] = __shfl(gsum, g * 8);

    int selmask = 0;
#pragma unroll
    for (int g = 0; g < 8; ++g) {
        int rank = 0;
#pragma unroll
        for (int h = 0; h < 8; ++h)
            rank += (gs[h] > gs[g]) || (gs[h] == gs[g] && h < g);
        if (rank < TOPK_GROUP) selmask |= 1 << g;
    }

    const int mygrp = lane >> 3;
    float val[4];
#pragma unroll
    for (int j = 0; j < 4; ++j)
        val[j] = ((selmask >> mygrp) & 1) ? sc[j] : -INFINITY;

    float wsel[TOP_K];
    int isel[TOP_K];
    float denom = 1e-20f;
#pragma unroll
    for (int it = 0; it < TOP_K; ++it) {
        float bvv = val[0];
        int bi = lane * 4;
#pragma unroll
        for (int j = 1; j < 4; ++j)
            if (val[j] > bvv) { bvv = val[j]; bi = lane * 4 + j; }
#pragma unroll
        for (int o = 1; o < 64; o <<= 1) {
            float ov = __shfl_xor(bvv, o);
            int oi = __shfl_xor(bi, o);
            if (ov > bvv || (ov == bvv && oi < bi)) { bvv = ov; bi = oi; }
        }
        isel[it] = bi;
        int q = bi & 3, ol = bi >> 2;
        float sv = (q == 0) ? s[0] : (q == 1) ? s[1] : (q == 2) ? s[2] : s[3];
        float w = __shfl(sv, ol);
        wsel[it] = w;
        denom += w;
        if (lane == ol) {
            if (q == 0) val[0] = -INFINITY;
            else if (q == 1) val[1] = -INFINITY;
            else if (q == 2) val[2] = -INFINITY;
            else val[3] = -INFINITY;
        }
    }

    if (lane == 0) {
        float scale = 2.5f / denom;
        long base = (long)t * TOP_K;
        long wbase = (long)T * TOP_K + base;
#pragma unroll
        for (int it = 0; it < TOP_K; ++it) {
            out[base + it] = (float)isel[it];
            out[wbase + it] = wsel[it] * scale;
        }
    }
}

extern "C" void kernel_launch(void* const* d_in, const int* in_sizes, int n_in,
                              void* d_out, int out_size, void* d_ws, size_t ws_size,
                              hipStream_t stream) {
    const float* X = (const float*)d_in[0];     // [T, 7168] fp32
    const float* W = (const float*)d_in[1];     // [256, 7168] fp32
    const float* bias = (const float*)d_in[2];  // [256] fp32
    float* out = (float*)d_out;

    const int K = in_sizes[1] / N_EXPERTS;  // 7168
    const int T = in_sizes[0] / K;          // 8192

    float* part = (float*)d_ws;                                    // 32 MB
    unsigned short* Wb = (unsigned short*)((char*)d_ws + (size_t)NCHUNK * T * N_EXPERTS * 4);  // 7.34 MB

    convert_w<<<(N_EXPERTS * (KDIM / 8)) / 256, 256, 0, stream>>>(W, Wb);
    gemm_mfma<<<(T / BM) * NCHUNK, 512, 0, stream>>>(X, Wb, part, T);
    routing_kernel<<<T / 4, 256, 0, stream>>>(part, bias, out, T);
}